// Round 1
// baseline (4187.299 us; speedup 1.0000x reference)
//
#include <hip/hip_runtime.h>

#define NN 50000
#define NE 800000
#define DIM 128
#define NEG_SLOPE 0.1f

// ---------- preprocessing ----------

__global__ void k_init_deg(float* __restrict__ deg) {
    int i = blockIdx.x * 256 + threadIdx.x;
    if (i < NN) deg[i] = 1.0f;  // self-loop weight
}

__global__ void k_edge_w(const int* __restrict__ ei, const float* __restrict__ attr,
                         const int* __restrict__ etype, const float* __restrict__ scale,
                         float* __restrict__ coef, float* __restrict__ deg) {
    int e = blockIdx.x * 256 + threadIdx.x;
    if (e >= NE) return;
    float w = scale[etype[e]] * attr[e];
    coef[e] = w;
    atomicAdd(&deg[ei[NE + e]], w);
}

__global__ void k_dinv(float* __restrict__ deg) {
    int i = blockIdx.x * 256 + threadIdx.x;
    if (i >= NN) return;
    float d = deg[i];
    deg[i] = d > 0.0f ? (1.0f / sqrtf(d)) : 0.0f;
}

__global__ void k_norm(const int* __restrict__ ei, float* __restrict__ coef,
                       const float* __restrict__ dinv) {
    int e = blockIdx.x * 256 + threadIdx.x;
    if (e >= NE) return;
    coef[e] = dinv[ei[e]] * coef[e] * dinv[ei[NE + e]];
}

__global__ void k_zero(float* __restrict__ p) {
    int i = blockIdx.x * 256 + threadIdx.x;   // float4 index
    float4 z = {0.f, 0.f, 0.f, 0.f};
    if (i < NN * DIM / 4) ((float4*)p)[i] = z;
}

// ---------- aggregation: t[dst] += norm_e * xin[src]  (edge part only) ----------
// 32 lanes per edge, 4 cols per lane (float4 gather + 4 atomics).
__global__ __launch_bounds__(256)
void k_scatter(const float* __restrict__ xin, const float* __restrict__ coef,
               const int* __restrict__ ei, float* __restrict__ t) {
    int g = blockIdx.x * 8 + (threadIdx.x >> 5);
    if (g >= NE) return;
    int lane = threadIdx.x & 31;
    float c = coef[g];
    int s = ei[g], d = ei[NE + g];
    float4 hv = *(const float4*)&xin[s * DIM + lane * 4];
    float* o = &t[d * DIM + lane * 4];
    atomicAdd(o + 0, c * hv.x);
    atomicAdd(o + 1, c * hv.y);
    atomicAdd(o + 2, c * hv.z);
    atomicAdd(o + 3, c * hv.w);
}

// ---------- transform: out = (t + dinv^2 * xin) @ W + b, optional leaky ----------
// 32 rows x 128 cols per block; acc[4][4] per thread; X in LDS, W via L1/L2.
template<bool LEAKY>
__global__ __launch_bounds__(256)
void k_transform(const float* __restrict__ t, const float* __restrict__ xin,
                 const float* __restrict__ W, const float* __restrict__ b,
                 const float* __restrict__ dinv, float* __restrict__ out) {
    __shared__ float Xs[32][132];
    int tid = threadIdx.x;
    int row0 = blockIdx.x * 32;

    // stage X_comb = t + dinv^2 * xin  (self-loop folded in here)
    #pragma unroll
    for (int j = 0; j < 4; ++j) {
        int f = tid + j * 256;            // float4 slot 0..1023
        int r = f >> 5, c4 = (f & 31) * 4;
        int row = row0 + r; if (row > NN - 1) row = NN - 1;
        float di = dinv[row];
        float dd = di * di;
        float4 tv = *(const float4*)&t[row * DIM + c4];
        float4 xv = *(const float4*)&xin[row * DIM + c4];
        float4 v;
        v.x = tv.x + dd * xv.x; v.y = tv.y + dd * xv.y;
        v.z = tv.z + dd * xv.z; v.w = tv.w + dd * xv.w;
        *(float4*)&Xs[r][c4] = v;
    }
    __syncthreads();

    int tx = tid & 31, ty = tid >> 5;     // tx: col group (4 cols), ty: row group (4 rows)
    float acc[4][4] = {};
    for (int k = 0; k < DIM; k += 4) {
        float4 xv[4];
        #pragma unroll
        for (int r = 0; r < 4; ++r) xv[r] = *(const float4*)&Xs[ty * 4 + r][k];
        #pragma unroll
        for (int kk = 0; kk < 4; ++kk) {
            float4 wv = *(const float4*)&W[(k + kk) * DIM + tx * 4];
            #pragma unroll
            for (int r = 0; r < 4; ++r) {
                float xs = (&xv[r].x)[kk];
                acc[r][0] = fmaf(xs, wv.x, acc[r][0]);
                acc[r][1] = fmaf(xs, wv.y, acc[r][1]);
                acc[r][2] = fmaf(xs, wv.z, acc[r][2]);
                acc[r][3] = fmaf(xs, wv.w, acc[r][3]);
            }
        }
    }

    float4 bv = *(const float4*)&b[tx * 4];
    #pragma unroll
    for (int r = 0; r < 4; ++r) {
        int row = row0 + ty * 4 + r;
        if (row >= NN) continue;
        float4 v;
        v.x = acc[r][0] + bv.x; v.y = acc[r][1] + bv.y;
        v.z = acc[r][2] + bv.z; v.w = acc[r][3] + bv.w;
        if (LEAKY) {
            v.x = v.x > 0.f ? v.x : NEG_SLOPE * v.x;
            v.y = v.y > 0.f ? v.y : NEG_SLOPE * v.y;
            v.z = v.z > 0.f ? v.z : NEG_SLOPE * v.z;
            v.w = v.w > 0.f ? v.w : NEG_SLOPE * v.w;
        }
        *(float4*)&out[row * DIM + tx * 4] = v;
    }
}

extern "C" void kernel_launch(void* const* d_in, const int* in_sizes, int n_in,
                              void* d_out, int out_size, void* d_ws, size_t ws_size,
                              hipStream_t stream) {
    const float* x     = (const float*)d_in[0];
    const int*   ei    = (const int*)d_in[1];     // [2, NE]: src then dst
    const float* attr  = (const float*)d_in[2];
    const int*   etype = (const int*)d_in[3];
    const float* scale = (const float*)d_in[4];
    const float* W1 = (const float*)d_in[5];
    const float* b1 = (const float*)d_in[6];
    const float* W2 = (const float*)d_in[7];
    const float* b2 = (const float*)d_in[8];
    const float* W3 = (const float*)d_in[9];
    const float* b3 = (const float*)d_in[10];
    float* out = (float*)d_out;

    float* dinv = (float*)d_ws;        // NN floats (deg, then dinv in-place)
    float* coef = dinv + NN;           // NE floats (w, then norm in-place)
    float* B1   = coef + NE;           // NN*DIM: aggregation target t
    float* B2   = B1 + NN * DIM;       // NN*DIM: intermediate activations

    const int nb_n = (NN + 255) / 256;
    const int nb_e = NE / 256;         // 3125 exact
    const int nb_s = NE / 8;           // 100000 exact
    const int nb_t = (NN + 31) / 32;   // 1563
    const int nb_z = (NN * DIM / 4 + 255) / 256;

    k_init_deg<<<nb_n, 256, 0, stream>>>(dinv);
    k_edge_w<<<nb_e, 256, 0, stream>>>(ei, attr, etype, scale, coef, dinv);
    k_dinv<<<nb_n, 256, 0, stream>>>(dinv);
    k_norm<<<nb_e, 256, 0, stream>>>(ei, coef, dinv);

    // layer 1: agg(x) -> B1 ; B2 = leaky((B1 + dinv^2 x) @ W1 + b1)
    k_zero<<<nb_z, 256, 0, stream>>>(B1);
    k_scatter<<<nb_s, 256, 0, stream>>>(x, coef, ei, B1);
    k_transform<true><<<nb_t, 256, 0, stream>>>(B1, x, W1, b1, dinv, B2);

    // layer 2: agg(B2) -> B1 ; B2 = leaky((B1 + dinv^2 B2) @ W2 + b2)  (in-place, row-tiled)
    k_zero<<<nb_z, 256, 0, stream>>>(B1);
    k_scatter<<<nb_s, 256, 0, stream>>>(B2, coef, ei, B1);
    k_transform<true><<<nb_t, 256, 0, stream>>>(B1, B2, W2, b2, dinv, B2);

    // layer 3: agg(B2) -> B1 ; out = (B1 + dinv^2 B2) @ W3 + b3
    k_zero<<<nb_z, 256, 0, stream>>>(B1);
    k_scatter<<<nb_s, 256, 0, stream>>>(B2, coef, ei, B1);
    k_transform<false><<<nb_t, 256, 0, stream>>>(B1, B2, W3, b3, dinv, out);
}

// Round 2
// 418.213 us; speedup vs baseline: 10.0124x; 10.0124x over previous
//
#include <hip/hip_runtime.h>

#define NN 50000
#define NE 800000
#define DIM 128
#define NEG_SLOPE 0.1f

// ---------- preprocessing: CSR-by-dst build ----------

__global__ void k_init(float* __restrict__ deg, int* __restrict__ hist) {
    int i = blockIdx.x * 256 + threadIdx.x;
    if (i < NN) { deg[i] = 1.0f; hist[i] = 0; }   // self-loop weight 1
}

__global__ void k_deg_hist(const int* __restrict__ ei, const float* __restrict__ attr,
                           const int* __restrict__ etype, const float* __restrict__ scale,
                           float* __restrict__ deg, int* __restrict__ hist) {
    int e = blockIdx.x * 256 + threadIdx.x;
    if (e >= NE) return;
    float w = scale[etype[e]] * attr[e];
    int d = ei[NE + e];
    atomicAdd(&deg[d], w);
    atomicAdd(&hist[d], 1);
}

__global__ void k_dinv(float* __restrict__ deg) {
    int i = blockIdx.x * 256 + threadIdx.x;
    if (i >= NN) return;
    float d = deg[i];
    deg[i] = d > 0.0f ? (1.0f / sqrtf(d)) : 0.0f;
}

// scan1: per-block (1024 elems) exclusive scan -> rowptr, block sums -> aux
__global__ void k_scan1(const int* __restrict__ hist, int* __restrict__ rowptr,
                        int* __restrict__ aux) {
    __shared__ int sdata[256];
    int t = threadIdx.x;
    int base = blockIdx.x * 1024 + t * 4;
    int v[4]; int s = 0;
    #pragma unroll
    for (int j = 0; j < 4; ++j) { v[j] = (base + j < NN) ? hist[base + j] : 0; s += v[j]; }
    sdata[t] = s;
    __syncthreads();
    for (int off = 1; off < 256; off <<= 1) {
        int x = (t >= off) ? sdata[t - off] : 0;
        __syncthreads();
        sdata[t] += x;
        __syncthreads();
    }
    int run = sdata[t] - s;  // exclusive prefix of this thread's chunk
    if (t == 255) aux[blockIdx.x] = sdata[255];
    #pragma unroll
    for (int j = 0; j < 4; ++j) { if (base + j < NN) rowptr[base + j] = run; run += v[j]; }
}

// scan2: exclusive scan of 49 block sums (one wave)
__global__ void k_scan2(int* __restrict__ aux) {
    int t = threadIdx.x;
    int v = (t < 49) ? aux[t] : 0;
    int orig = v;
    for (int off = 1; off < 64; off <<= 1) {
        int y = __shfl_up(v, off, 64);
        if (t >= off) v += y;
    }
    if (t < 49) aux[t] = v - orig;
}

// scan3: add block offsets; init cursor (hist) = rowptr; set rowptr[NN]=NE
__global__ void k_scan3(int* __restrict__ rowptr, int* __restrict__ hist,
                        const int* __restrict__ aux) {
    int i = blockIdx.x * 256 + threadIdx.x;
    if (i < NN) {
        int v = rowptr[i] + aux[i >> 10];
        rowptr[i] = v;
        hist[i] = v;
    }
    if (i == 0) rowptr[NN] = NE;
}

// place edges into CSR order; compute normalized coefficient on the fly
__global__ void k_place(const int* __restrict__ ei, const float* __restrict__ attr,
                        const int* __restrict__ etype, const float* __restrict__ scale,
                        const float* __restrict__ dinv, int* __restrict__ cursor,
                        int* __restrict__ srcs, float* __restrict__ coefs) {
    int e = blockIdx.x * 256 + threadIdx.x;
    if (e >= NE) return;
    int s = ei[e], d = ei[NE + e];
    float w = scale[etype[e]] * attr[e];
    float nrm = dinv[s] * w * dinv[d];
    int pos = atomicAdd(&cursor[d], 1);
    srcs[pos] = s;
    coefs[pos] = nrm;
}

// ---------- fused layer: out = leaky?( (agg(xin) + dinv^2 xin) @ W + b ) ----------
// Block = 256 threads = 4 waves; 32 dst rows per block.
// Phase 1: wave w aggregates rows w*8..w*8+7, lane owns 2 columns (float2).
// Phase 2: 32x128 @ 128x128 register-blocked GEMM from LDS.
template<bool LEAKY>
__global__ __launch_bounds__(256)
void k_layer(const float* __restrict__ xin, const float* __restrict__ coefs,
             const int* __restrict__ srcs, const int* __restrict__ rowptr,
             const float* __restrict__ dinv, const float* __restrict__ W,
             const float* __restrict__ b, float* __restrict__ out) {
    __shared__ float Xs[32][132];
    int tid = threadIdx.x;
    int row0 = blockIdx.x * 32;
    int wv = tid >> 6;
    int lane = tid & 63;

    // phase 1: aggregate
    for (int rr = 0; rr < 8; ++rr) {
        int r = wv * 8 + rr;
        int row = row0 + r;
        float ax = 0.f, ay = 0.f;
        if (row < NN) {
            float di = dinv[row];
            float2 sv = *(const float2*)&xin[row * DIM + lane * 2];
            ax = di * di * sv.x;
            ay = di * di * sv.y;
            int p = rowptr[row], p1 = rowptr[row + 1];
            for (; p + 3 < p1; p += 4) {
                float c0 = coefs[p], c1 = coefs[p + 1], c2 = coefs[p + 2], c3 = coefs[p + 3];
                int s0 = srcs[p], s1 = srcs[p + 1], s2 = srcs[p + 2], s3 = srcs[p + 3];
                float2 v0 = *(const float2*)&xin[s0 * DIM + lane * 2];
                float2 v1 = *(const float2*)&xin[s1 * DIM + lane * 2];
                float2 v2 = *(const float2*)&xin[s2 * DIM + lane * 2];
                float2 v3 = *(const float2*)&xin[s3 * DIM + lane * 2];
                ax = fmaf(c0, v0.x, ax); ay = fmaf(c0, v0.y, ay);
                ax = fmaf(c1, v1.x, ax); ay = fmaf(c1, v1.y, ay);
                ax = fmaf(c2, v2.x, ax); ay = fmaf(c2, v2.y, ay);
                ax = fmaf(c3, v3.x, ax); ay = fmaf(c3, v3.y, ay);
            }
            for (; p < p1; ++p) {
                float c = coefs[p];
                int s = srcs[p];
                float2 v = *(const float2*)&xin[s * DIM + lane * 2];
                ax = fmaf(c, v.x, ax);
                ay = fmaf(c, v.y, ay);
            }
        }
        float2 res; res.x = ax; res.y = ay;
        *(float2*)&Xs[r][lane * 2] = res;
    }
    __syncthreads();

    // phase 2: GEMM
    int tx = tid & 31, ty = tid >> 5;
    float acc[4][4] = {};
    for (int k = 0; k < DIM; k += 4) {
        float4 xv[4];
        #pragma unroll
        for (int r = 0; r < 4; ++r) xv[r] = *(const float4*)&Xs[ty * 4 + r][k];
        #pragma unroll
        for (int kk = 0; kk < 4; ++kk) {
            float4 wv2 = *(const float4*)&W[(k + kk) * DIM + tx * 4];
            #pragma unroll
            for (int r = 0; r < 4; ++r) {
                float xs = (&xv[r].x)[kk];
                acc[r][0] = fmaf(xs, wv2.x, acc[r][0]);
                acc[r][1] = fmaf(xs, wv2.y, acc[r][1]);
                acc[r][2] = fmaf(xs, wv2.z, acc[r][2]);
                acc[r][3] = fmaf(xs, wv2.w, acc[r][3]);
            }
        }
    }

    float4 bv = *(const float4*)&b[tx * 4];
    #pragma unroll
    for (int r = 0; r < 4; ++r) {
        int row = row0 + ty * 4 + r;
        if (row >= NN) continue;
        float4 v;
        v.x = acc[r][0] + bv.x; v.y = acc[r][1] + bv.y;
        v.z = acc[r][2] + bv.z; v.w = acc[r][3] + bv.w;
        if (LEAKY) {
            v.x = v.x > 0.f ? v.x : NEG_SLOPE * v.x;
            v.y = v.y > 0.f ? v.y : NEG_SLOPE * v.y;
            v.z = v.z > 0.f ? v.z : NEG_SLOPE * v.z;
            v.w = v.w > 0.f ? v.w : NEG_SLOPE * v.w;
        }
        *(float4*)&out[row * DIM + tx * 4] = v;
    }
}

extern "C" void kernel_launch(void* const* d_in, const int* in_sizes, int n_in,
                              void* d_out, int out_size, void* d_ws, size_t ws_size,
                              hipStream_t stream) {
    const float* x     = (const float*)d_in[0];
    const int*   ei    = (const int*)d_in[1];
    const float* attr  = (const float*)d_in[2];
    const int*   etype = (const int*)d_in[3];
    const float* scale = (const float*)d_in[4];
    const float* W1 = (const float*)d_in[5];
    const float* b1 = (const float*)d_in[6];
    const float* W2 = (const float*)d_in[7];
    const float* b2 = (const float*)d_in[8];
    const float* W3 = (const float*)d_in[9];
    const float* b3 = (const float*)d_in[10];
    float* out = (float*)d_out;

    // ws layout (all 4B elems, 16B-aligned sections):
    float* B2     = (float*)d_ws;              // NN*DIM
    float* coefs  = B2 + NN * DIM;             // NE
    float* dinv   = coefs + NE;                // NN (deg -> dinv in place)
    int*   srcs   = (int*)(dinv + NN);         // NE
    int*   hist   = srcs + NE;                 // NN (hist -> cursor)
    int*   rowptr = hist + NN;                 // NN+1
    int*   aux    = rowptr + NN + 1;           // 64

    const int nb_n = (NN + 255) / 256;         // 196
    const int nb_e = NE / 256;                 // 3125
    const int nb_l = (NN + 31) / 32;           // 1563
    const int nb_s1 = (NN + 1023) / 1024;      // 49

    k_init<<<nb_n, 256, 0, stream>>>(dinv, hist);
    k_deg_hist<<<nb_e, 256, 0, stream>>>(ei, attr, etype, scale, dinv, hist);
    k_dinv<<<nb_n, 256, 0, stream>>>(dinv);
    k_scan1<<<nb_s1, 256, 0, stream>>>(hist, rowptr, aux);
    k_scan2<<<1, 64, 0, stream>>>(aux);
    k_scan3<<<nb_n, 256, 0, stream>>>(rowptr, hist, aux);
    k_place<<<nb_e, 256, 0, stream>>>(ei, attr, etype, scale, dinv, hist, srcs, coefs);

    // layer 1: x -> d_out ; layer 2: d_out -> B2 ; layer 3: B2 -> d_out
    k_layer<true ><<<nb_l, 256, 0, stream>>>(x,   coefs, srcs, rowptr, dinv, W1, b1, out);
    k_layer<true ><<<nb_l, 256, 0, stream>>>(out, coefs, srcs, rowptr, dinv, W2, b2, B2);
    k_layer<false><<<nb_l, 256, 0, stream>>>(B2,  coefs, srcs, rowptr, dinv, W3, b3, out);
}